// Round 9
// baseline (621.524 us; speedup 1.0000x reference)
//
#include <hip/hip_runtime.h>
#include <hip/hip_bf16.h>

#define N_TOKENS 2048
#define D_IN 1024
#define D_HID 4096
#define D_OUT 1024
#define NE 8

typedef __attribute__((ext_vector_type(8))) short s16x8;
typedef __attribute__((ext_vector_type(4))) float f32x4;

__device__ inline unsigned short f2bf(float f) {
  union { float f; unsigned u; } v; v.f = f;
  unsigned u = v.u;
  unsigned r = u + 0x7fff + ((u >> 16) & 1);   // round-to-nearest-even
  return (unsigned short)(r >> 16);
}

#define GLDS16(gp, lp)                                                          \
  __builtin_amdgcn_global_load_lds(                                             \
      (const __attribute__((address_space(1))) unsigned int*)(gp),              \
      (__attribute__((address_space(3))) unsigned int*)(lp), 16, 0, 0)

// ---------------------------------------------------------------- router ----
__global__ __launch_bounds__(256) void router_kernel(
    const float* __restrict__ x, const float* __restrict__ Wr,
    const float* __restrict__ br, int* __restrict__ cnt, int* __restrict__ tids,
    int4* __restrict__ meta, float2* __restrict__ tw) {
  int wid = threadIdx.x >> 6, lane = threadIdx.x & 63;
  int n = blockIdx.x * 4 + wid;
  const float* xr = x + (size_t)n * D_IN;
  float acc[NE];
#pragma unroll
  for (int e = 0; e < NE; e++) acc[e] = 0.f;
  for (int i = lane; i < D_IN; i += 64) {
    float xv = xr[i];
    const float4* wr = (const float4*)(Wr + (size_t)i * NE);
    float4 w0 = wr[0], w1 = wr[1];
    acc[0] += xv * w0.x; acc[1] += xv * w0.y;
    acc[2] += xv * w0.z; acc[3] += xv * w0.w;
    acc[4] += xv * w1.x; acc[5] += xv * w1.y;
    acc[6] += xv * w1.z; acc[7] += xv * w1.w;
  }
#pragma unroll
  for (int e = 0; e < NE; e++) {
#pragma unroll
    for (int s = 32; s; s >>= 1) acc[e] += __shfl_xor(acc[e], s, 64);
  }
  if (lane == 0) {
    float lg[NE], p[NE];
    float m = -1e30f;
#pragma unroll
    for (int e = 0; e < NE; e++) { lg[e] = acc[e] + br[e]; m = fmaxf(m, lg[e]); }
    float s = 0.f;
#pragma unroll
    for (int e = 0; e < NE; e++) { p[e] = expf(lg[e] - m); s += p[e]; }
    float inv = 1.f / s;
    int i0 = 0;
#pragma unroll
    for (int e = 1; e < NE; e++) if (lg[e] > lg[i0]) i0 = e;
    int i1 = (i0 == 0) ? 1 : 0;
#pragma unroll
    for (int e = 0; e < NE; e++) if (e != i0 && lg[e] > lg[i1]) i1 = e;
    int p0 = atomicAdd(&cnt[i0], 1);
    int p1 = atomicAdd(&cnt[i1], 1);
    tids[i0 * N_TOKENS + p0] = n;
    tids[i1 * N_TOKENS + p1] = n;
    meta[n] = make_int4(i0, p0, i1, p1);
    tw[n] = make_float2(p[i0] * inv, p[i1] * inv);
  }
}

// ------------------------------------------------------------- conversions ----
__global__ __launch_bounds__(256) void convx_kernel(const float* __restrict__ x,
                                                    short* __restrict__ xb) {
  int i = (blockIdx.x * 256 + threadIdx.x) * 4;
  float4 v = *(const float4*)(x + i);
  short4 o;
  o.x = (short)f2bf(v.x); o.y = (short)f2bf(v.y);
  o.z = (short)f2bf(v.z); o.w = (short)f2bf(v.w);
  *(short4*)(xb + i) = o;
}

// src [R][C] f32 (per expert slab), dst [C][R] bf16. float4 loads, short4 writes.
__global__ __launch_bounds__(256) void transconv_kernel(
    const float* __restrict__ src, short* __restrict__ dst, int R, int C) {
  __shared__ float tile[64][65];
  size_t eoff = (size_t)blockIdx.z * R * C;
  int r0 = blockIdx.y * 64, c0 = blockIdx.x * 64;
  const float* s = src + eoff + (size_t)r0 * C + c0;
  int t = threadIdx.x;
  int lc4 = (t & 15) * 4;
  int lr16 = t >> 4;
#pragma unroll
  for (int p = 0; p < 4; p++) {
    int r = p * 16 + lr16;
    float4 v = *(const float4*)(s + (size_t)r * C + lc4);
    tile[r][lc4 + 0] = v.x; tile[r][lc4 + 1] = v.y;
    tile[r][lc4 + 2] = v.z; tile[r][lc4 + 3] = v.w;
  }
  __syncthreads();
  short* d = dst + eoff + (size_t)c0 * R + r0;
  int rr4 = (t & 15) * 4;
  int cc = t >> 4;
#pragma unroll
  for (int p = 0; p < 4; p++) {
    int c = p * 16 + cc;
    short4 o;
    o.x = (short)f2bf(tile[rr4 + 0][c]);
    o.y = (short)f2bf(tile[rr4 + 1][c]);
    o.z = (short)f2bf(tile[rr4 + 2][c]);
    o.w = (short)f2bf(tile[rr4 + 3][c]);
    *(short4*)(d + (size_t)c * R + rr4) = o;
  }
}

// ------------------------------------------------------------------ GEMM1 ----
// BK=32, 4 buffers (64 KiB LDS, depth-4 prefetch), counted vmcnt 12/8/4/0.
__global__ __launch_bounds__(256) void gemm1_kernel(
    const short* __restrict__ xb,   // [2048][1024] bf16
    const short* __restrict__ W1b,  // [8][4096][1024] bf16 (n-major)
    const float* __restrict__ b1,   // [8][4096]
    const int* __restrict__ cnt, const int* __restrict__ tids,
    short* __restrict__ H) {        // [4096][4096] bf16 compact
  const int NT_M = N_TOKENS / 128, NT_N = D_HID / 128;
  int bid0 = blockIdx.x;
  int bid = (bid0 & 7) * ((NE * NT_M * NT_N) >> 3) + (bid0 >> 3);
  int e = bid / (NT_M * NT_N);
  int r2 = bid % (NT_M * NT_N);
  int mt = r2 % NT_M, nt = r2 / NT_M;
  int ce = cnt[e];
  if (mt * 128 >= ce) return;
  int off = 0;
  for (int i = 0; i < e; i++) off += cnt[i];

  __shared__ alignas(16) short As[4][128][32];
  __shared__ alignas(16) short Bs[4][128][32];

  int lane = threadIdx.x & 63, wid = threadIdx.x >> 6;
  int wr = wid >> 1, wc = wid & 1;
  int srow = lane >> 2;
  int gch = ((lane & 3) ^ ((lane >> 3) & 3)) * 8;  // pre-swizzled source chunk

  const int* tlist = tids + e * N_TOKENS + mt * 128;
  const short* a_src[2];
  const short* b_src[2];
#pragma unroll
  for (int j = 0; j < 2; j++) {
    int r = (wid + 4 * j) * 16 + srow;
    int t = (mt * 128 + r < ce) ? tlist[r] : tlist[0];
    a_src[j] = xb + (size_t)t * D_IN + gch;
    b_src[j] = W1b + (size_t)e * D_HID * D_IN + (size_t)(nt * 128 + r) * D_IN + gch;
  }

  f32x4 zero = {0.f, 0.f, 0.f, 0.f};
  f32x4 acc[4][4];
#pragma unroll
  for (int i = 0; i < 4; i++)
#pragma unroll
    for (int j = 0; j < 4; j++) acc[i][j] = zero;

#define STAGE1(ks, buf)                                                         \
  {                                                                             \
    int k0 = (ks) * 32;                                                         \
    GLDS16(a_src[0] + k0, &As[buf][wid * 16][0]);                               \
    GLDS16(a_src[1] + k0, &As[buf][(wid + 4) * 16][0]);                         \
    GLDS16(b_src[0] + k0, &Bs[buf][wid * 16][0]);                               \
    GLDS16(b_src[1] + k0, &Bs[buf][(wid + 4) * 16][0]);                         \
  }

  const int NK = D_IN / 32;  // 32
  STAGE1(0, 0); STAGE1(1, 1); STAGE1(2, 2); STAGE1(3, 3);
  int chsh = (((lane >> 4) ^ ((lane >> 1) & 3)) & 3) * 8;
  int arow = wr * 64 + (lane & 15), brow = wc * 64 + (lane & 15);
  for (int ks = 0; ks < NK; ks++) {
    if (ks < NK - 3)      asm volatile("s_waitcnt vmcnt(12)" : : : "memory");
    else if (ks == NK - 3) asm volatile("s_waitcnt vmcnt(8)" : : : "memory");
    else if (ks == NK - 2) asm volatile("s_waitcnt vmcnt(4)" : : : "memory");
    else                   asm volatile("s_waitcnt vmcnt(0)" : : : "memory");
    __builtin_amdgcn_s_barrier();
    int cb = ks & 3;
    s16x8 a[4], b[4];
#pragma unroll
    for (int i = 0; i < 4; i++)
      a[i] = *(const s16x8*)&As[cb][arow + i * 16][chsh];
#pragma unroll
    for (int j = 0; j < 4; j++)
      b[j] = *(const s16x8*)&Bs[cb][brow + j * 16][chsh];
    __builtin_amdgcn_s_setprio(1);
#pragma unroll
    for (int i = 0; i < 4; i++)
#pragma unroll
      for (int j = 0; j < 4; j++)
        acc[i][j] = __builtin_amdgcn_mfma_f32_16x16x32_bf16(a[i], b[j], acc[i][j], 0, 0, 0);
    __builtin_amdgcn_s_setprio(0);
    __builtin_amdgcn_s_barrier();
    if (ks + 4 < NK) STAGE1(ks + 4, cb);
  }

  int lr = (lane >> 4) * 4, lc = lane & 15;
#pragma unroll
  for (int j = 0; j < 4; j++) {
    int col = nt * 128 + wc * 64 + j * 16 + lc;
    float bias = b1[e * D_HID + col];
#pragma unroll
    for (int i = 0; i < 4; i++) {
#pragma unroll
      for (int r = 0; r < 4; r++) {
        int grow = mt * 128 + wr * 64 + i * 16 + lr + r;
        if (grow < ce) {
          float v = fmaxf(acc[i][j][r] + bias, 0.f);
          H[(size_t)(off + grow) * D_HID + col] = (short)f2bf(v);
        }
      }
    }
  }
}

// ------------------------------------------------------------------ GEMM2 ----
// K-split x4 (each block K=1024, NK=32) -> 1024 blocks. Partials to 4 Y slabs.
__global__ __launch_bounds__(256) void gemm2_kernel(
    const short* __restrict__ H,    // [4096][4096] bf16
    const short* __restrict__ W2b,  // [8][1024][4096] bf16 (n-major)
    const int* __restrict__ cnt,
    float* __restrict__ Y) {        // [4][4096][1024] f32 partials
  const int NT_M = N_TOKENS / 128, NT_N = D_OUT / 128;
  const int PER_E = 4 * NT_M * NT_N;  // 512... (4 kh x 16 mt x 8 nt? no: 4*16*8)
  int bid0 = blockIdx.x;
  int bid = (bid0 & 7) * ((NE * PER_E) >> 3) + (bid0 >> 3);
  int e = bid / PER_E;
  int r2 = bid % PER_E;
  int kh = r2 / (NT_M * NT_N);
  int r3 = r2 % (NT_M * NT_N);
  int mt = r3 % NT_M, nt = r3 / NT_M;
  int ce = cnt[e];
  if (mt * 128 >= ce) return;
  int off = 0;
  for (int i = 0; i < e; i++) off += cnt[i];

  __shared__ alignas(16) short As[4][128][32];
  __shared__ alignas(16) short Bs[4][128][32];

  int lane = threadIdx.x & 63, wid = threadIdx.x >> 6;
  int wr = wid >> 1, wc = wid & 1;
  int srow = lane >> 2;
  int gch = ((lane & 3) ^ ((lane >> 3) & 3)) * 8;
  size_t kbase = (size_t)kh * 1024;

  const short* a_src[2];
  const short* b_src[2];
#pragma unroll
  for (int j = 0; j < 2; j++) {
    int r = (wid + 4 * j) * 16 + srow;
    int grow = mt * 128 + r;
    if (grow > ce - 1) grow = ce - 1;
    a_src[j] = H + (size_t)(off + grow) * D_HID + kbase + gch;
    b_src[j] = W2b + (size_t)e * D_OUT * D_HID + (size_t)(nt * 128 + r) * D_HID + kbase + gch;
  }

  f32x4 zero = {0.f, 0.f, 0.f, 0.f};
  f32x4 acc[4][4];
#pragma unroll
  for (int i = 0; i < 4; i++)
#pragma unroll
    for (int j = 0; j < 4; j++) acc[i][j] = zero;

#define STAGE2(ks, buf)                                                         \
  {                                                                             \
    int k0 = (ks) * 32;                                                         \
    GLDS16(a_src[0] + k0, &As[buf][wid * 16][0]);                               \
    GLDS16(a_src[1] + k0, &As[buf][(wid + 4) * 16][0]);                         \
    GLDS16(b_src[0] + k0, &Bs[buf][wid * 16][0]);                               \
    GLDS16(b_src[1] + k0, &Bs[buf][(wid + 4) * 16][0]);                         \
  }

  const int NK = 1024 / 32;  // 32
  STAGE2(0, 0); STAGE2(1, 1); STAGE2(2, 2); STAGE2(3, 3);
  int chsh = (((lane >> 4) ^ ((lane >> 1) & 3)) & 3) * 8;
  int arow = wr * 64 + (lane & 15), brow = wc * 64 + (lane & 15);
  for (int ks = 0; ks < NK; ks++) {
    if (ks < NK - 3)      asm volatile("s_waitcnt vmcnt(12)" : : : "memory");
    else if (ks == NK - 3) asm volatile("s_waitcnt vmcnt(8)" : : : "memory");
    else if (ks == NK - 2) asm volatile("s_waitcnt vmcnt(4)" : : : "memory");
    else                   asm volatile("s_waitcnt vmcnt(0)" : : : "memory");
    __builtin_amdgcn_s_barrier();
    int cb = ks & 3;
    s16x8 a[4], b[4];
#pragma unroll
    for (int i = 0; i < 4; i++)
      a[i] = *(const s16x8*)&As[cb][arow + i * 16][chsh];
#pragma unroll
    for (int j = 0; j < 4; j++)
      b[j] = *(const s16x8*)&Bs[cb][brow + j * 16][chsh];
    __builtin_amdgcn_s_setprio(1);
#pragma unroll
    for (int i = 0; i < 4; i++)
#pragma unroll
      for (int j = 0; j < 4; j++)
        acc[i][j] = __builtin_amdgcn_mfma_f32_16x16x32_bf16(a[i], b[j], acc[i][j], 0, 0, 0);
    __builtin_amdgcn_s_setprio(0);
    __builtin_amdgcn_s_barrier();
    if (ks + 4 < NK) STAGE2(ks + 4, cb);
  }

  float* Yh = Y + (size_t)kh * (2 * N_TOKENS) * D_OUT;
  int lr = (lane >> 4) * 4, lc = lane & 15;
#pragma unroll
  for (int j = 0; j < 4; j++) {
    int col = nt * 128 + wc * 64 + j * 16 + lc;
#pragma unroll
    for (int i = 0; i < 4; i++) {
#pragma unroll
      for (int r = 0; r < 4; r++) {
        int grow = mt * 128 + wr * 64 + i * 16 + lr + r;
        if (grow < ce) Yh[(size_t)(off + grow) * D_OUT + col] = acc[i][j][r];
      }
    }
  }
}

// ---------------------------------------------------------------- combine ----
__global__ __launch_bounds__(256) void combine_kernel(
    const float* __restrict__ Y, const float* __restrict__ b2,
    const int* __restrict__ cnt, const int4* __restrict__ meta,
    const float2* __restrict__ tw, float* __restrict__ out) {
  const size_t YH = (size_t)(2 * N_TOKENS) * D_OUT;
  int n = blockIdx.x;
  int4 m = meta[n];
  float2 w = tw[n];
  int off0 = 0, off1 = 0;
#pragma unroll
  for (int i = 0; i < NE; i++) {
    int c = cnt[i];
    if (i < m.x) off0 += c;
    if (i < m.z) off1 += c;
  }
  size_t r0 = (size_t)(off0 + m.y) * D_OUT;
  size_t r1 = (size_t)(off1 + m.w) * D_OUT;
  const float4* g0 = (const float4*)(b2 + (size_t)m.x * D_OUT);
  const float4* g1 = (const float4*)(b2 + (size_t)m.z * D_OUT);
  float4* o = (float4*)(out + (size_t)n * D_OUT);
  int d = threadIdx.x;
  float4 s0 = g0[d], s1 = g1[d];
#pragma unroll
  for (int h = 0; h < 4; h++) {
    float4 a = ((const float4*)(Y + h * YH + r0))[d];
    float4 b = ((const float4*)(Y + h * YH + r1))[d];
    s0.x += a.x; s0.y += a.y; s0.z += a.z; s0.w += a.w;
    s1.x += b.x; s1.y += b.y; s1.z += b.z; s1.w += b.w;
  }
  float4 r;
  r.x = w.x * s0.x + w.y * s1.x;
  r.y = w.x * s0.y + w.y * s1.y;
  r.z = w.x * s0.z + w.y * s1.z;
  r.w = w.x * s0.w + w.y * s1.w;
  o[d] = r;
}

// ----------------------------------------------------------------- launch ----
extern "C" void kernel_launch(void* const* d_in, const int* in_sizes, int n_in,
                              void* d_out, int out_size, void* d_ws, size_t ws_size,
                              hipStream_t stream) {
  const float* x  = (const float*)d_in[0];
  const float* Wr = (const float*)d_in[1];
  const float* br = (const float*)d_in[2];
  const float* W1 = (const float*)d_in[3];
  const float* b1 = (const float*)d_in[4];
  const float* W2 = (const float*)d_in[5];
  const float* b2 = (const float*)d_in[6];
  float* out = (float*)d_out;

  char* ws = (char*)d_ws;
  size_t o = 0;
  auto alloc = [&](size_t bytes) -> void* {
    o = (o + 255) & ~(size_t)255;
    void* p = ws + o;
    o += bytes;
    return p;
  };
  int*    cnt  = (int*)alloc(NE * 4);
  int*    tids = (int*)alloc((size_t)NE * N_TOKENS * 4);
  int4*   meta = (int4*)alloc((size_t)N_TOKENS * 16);
  float2* tw   = (float2*)alloc((size_t)N_TOKENS * 8);
  short*  xb   = (short*)alloc((size_t)N_TOKENS * D_IN * 2);
  short*  W2b  = (short*)alloc((size_t)NE * D_OUT * D_HID * 2);
  short*  H    = (short*)alloc((size_t)2 * N_TOKENS * D_HID * 2);
  // union region: W1b (64 MB, dead after gemm1) aliased with Y (67 MB, gemm2+)
  void*   uni  = alloc((size_t)4 * 2 * N_TOKENS * D_OUT * 4);
  short*  W1b  = (short*)uni;
  float*  Y    = (float*)uni;
  if (o > ws_size) return;  // workspace too small; fail loudly via wrong output

  hipMemsetAsync(cnt, 0, NE * 4, stream);
  router_kernel<<<N_TOKENS / 4, 256, 0, stream>>>(x, Wr, br, cnt, tids, meta, tw);
  convx_kernel<<<(N_TOKENS * D_IN / 4) / 256, 256, 0, stream>>>(x, xb);
  transconv_kernel<<<dim3(D_HID / 64, D_IN / 64, NE), 256, 0, stream>>>(W1, W1b, D_IN, D_HID);
  transconv_kernel<<<dim3(D_OUT / 64, D_HID / 64, NE), 256, 0, stream>>>(W2, W2b, D_HID, D_OUT);
  gemm1_kernel<<<NE * (N_TOKENS / 128) * (D_HID / 128), 256, 0, stream>>>(xb, W1b, b1, cnt, tids, H);
  gemm2_kernel<<<NE * (N_TOKENS / 128) * (D_OUT / 128) * 4, 256, 0, stream>>>(H, W2b, cnt, Y);
  combine_kernel<<<N_TOKENS, 256, 0, stream>>>(Y, b2, cnt, meta, tw, out);
}